// Round 4
// baseline (518.304 us; speedup 1.0000x reference)
//
#include <hip/hip_runtime.h>
#include <math.h>

#define B_ 8
#define K_ 100000
#define NANN 32
#define C_ 80
#define BLOCK 256
#define CHUNK 256           // anchors per block
#define LN2 0.69314718056f
#define NBLK_X ((K_ + CHUNK - 1) / CHUNK)
#define TOTAL_BLOCKS (NBLK_X * B_)

__global__ void zero_ws_kernel(float* ws) {
    int i = threadIdx.x;
    if (i < 3 * B_ + 1) ws[i] = 0.0f;   // 24 accumulators + 1 completion counter
}

__device__ __forceinline__ float fast_log2(float x) {
#if __has_builtin(__builtin_amdgcn_logf)
    return __builtin_amdgcn_logf(x);      // raw v_log_f32 (log2)
#else
    return __log2f(x);
#endif
}
__device__ __forceinline__ float fast_sqrt(float x) {
#if __has_builtin(__builtin_amdgcn_sqrtf)
    return __builtin_amdgcn_sqrtf(x);     // raw v_sqrt_f32
#else
    return sqrtf(x);
#endif
}

// LDS-only barrier: waits ds ops (lgkmcnt) but leaves global loads (vmcnt) in
// flight — unlike __syncthreads(), which drains vmcnt(0). Every barrier in this
// kernel only orders LDS (s_ann / s_m / s_red). All BAR() sites are in uniform
// control flow (no early return), so the raw s_barrier cannot deadlock.
#define BAR() do { \
    asm volatile("s_waitcnt lgkmcnt(0)" ::: "memory"); \
    __builtin_amdgcn_s_barrier(); \
} while (0)

__launch_bounds__(BLOCK)
__global__ void focal_main(const float* __restrict__ cls,
                           const float* __restrict__ reg,
                           const float* __restrict__ anc,
                           const float* __restrict__ ann,
                           float* __restrict__ ws,
                           float* __restrict__ out) {
    const int b     = blockIdx.y;
    const int chunk = blockIdx.x;
    const int tid   = threadIdx.x;

    __shared__ float s_ann[NANN * 5];
    __shared__ float s_m[CHUNK];               // 0 = ignore, 1 = count (neg or pos)
    __shared__ float s_red[(BLOCK / 64) * 3];

    const int k0 = chunk * CHUNK;
    const int k  = k0 + tid;
    const bool kval = (k < K_);

    // ---- early long-latency loads: anchor + annotation staging ----
    float4 a = make_float4(0.f, 0.f, 0.f, 0.f);
    if (kval) a = *(const float4*)(anc + (size_t)k * 4);

    // stage annotations as float4 (160 floats = 40 float4)
    if (tid < NANN * 5 / 4)
        ((float4*)s_ann)[tid] = ((const float4*)(ann + (size_t)b * NANN * 5))[tid];
    BAR();

    float reg_acc  = 0.0f;
    float np_acc   = 0.0f;
    float cls_corr = 0.0f;   // positive-anchor class-term swap (exact units)
    float m        = 0.0f;

    if (kval) {
        float aw = a.z - a.x, ah = a.w - a.y;
        float area_a = aw * ah;

        float best = -2.0f;
        int bestj = 0;
        for (int j = 0; j < NANN; ++j) {
            float bx1 = s_ann[j * 5 + 0], by1 = s_ann[j * 5 + 1];
            float bx2 = s_ann[j * 5 + 2], by2 = s_ann[j * 5 + 3];
            float lbl = s_ann[j * 5 + 4];
            float area_b = (bx2 - bx1) * (by2 - by1);
            float iw = fmaxf(fminf(a.z, bx2) - fmaxf(a.x, bx1), 0.0f);
            float ih = fmaxf(fminf(a.w, by2) - fmaxf(a.y, by1), 0.0f);
            float inter = iw * ih;
            float uni = fmaxf(area_a + area_b - inter, 1e-8f);
            float iou = inter / uni;
            if (lbl < 0.0f) iou = -1.0f;            // invalid annotation mask
            if (iou > best) { best = iou; bestj = j; }  // first-max = jnp.argmax
        }

        if (best >= 0.5f) {                         // positive anchor
            m = 1.0f;
            np_acc = 1.0f;
            int c = (int)s_ann[bestj * 5 + 4];
            // correction: sweep will apply the NEG formula at class c; swap it
            // for the POS formula. p in (0.01,0.99) -> clamp is a no-op.
            float p  = cls[((size_t)b * K_ + k) * C_ + c];
            float pm = 1.0f - p;
            float pos_term = -0.25f * fast_sqrt(pm) * (fast_log2(p)  * LN2);
            float neg_term = -0.75f * fast_sqrt(p)  * (fast_log2(pm) * LN2);
            cls_corr = pos_term - neg_term;

            // regression smooth-L1
            float gx1 = s_ann[bestj * 5 + 0], gy1 = s_ann[bestj * 5 + 1];
            float gx2 = s_ann[bestj * 5 + 2], gy2 = s_ann[bestj * 5 + 3];
            float gw = fmaxf(gx2 - gx1, 1.0f);
            float gh = fmaxf(gy2 - gy1, 1.0f);
            float gcx = gx1 + 0.5f * gw, gcy = gy1 + 0.5f * gh;
            float acx = a.x + 0.5f * aw, acy = a.y + 0.5f * ah;
            float4 r = *(const float4*)(reg + ((size_t)b * K_ + k) * 4);
            float t0 = ((gcx - acx) / aw) * 10.0f;
            float t1 = ((gcy - acy) / ah) * 10.0f;
            float t2 = (fast_log2(gw / aw) * LN2) * 5.0f;
            float t3 = (fast_log2(gh / ah) * LN2) * 5.0f;
            float d, s;
            d = fabsf(t0 - r.x); s = (d <= 1.0f/9.0f) ? 4.5f*d*d : d - 0.5f/9.0f; reg_acc += s;
            d = fabsf(t1 - r.y); s = (d <= 1.0f/9.0f) ? 4.5f*d*d : d - 0.5f/9.0f; reg_acc += s;
            d = fabsf(t2 - r.z); s = (d <= 1.0f/9.0f) ? 4.5f*d*d : d - 0.5f/9.0f; reg_acc += s;
            d = fabsf(t3 - r.w); s = (d <= 1.0f/9.0f) ? 4.5f*d*d : d - 0.5f/9.0f; reg_acc += s;
        } else if (best < 0.4f) {
            m = 1.0f;                               // negative anchor
        } // else ignore: m = 0
    }
    s_m[tid] = m;
    BAR();

    // ---- classification sweep: acc = sum m * sqrt(p) * log2(1-p) ----
    // Plain cached loads, compiler-scheduled (unroll 10 => 10 float4 loads in
    // flight per wave). Round-3 lesson: manual rolling prefetch + nontemporal
    // loads serialized on vmcnt and lost L3 residency (215 µs, 634 GB/s).
    const int na  = min(CHUNK, K_ - k0);
    const int nf4 = na * (C_ / 4);
    const float4* __restrict__ cp =
        (const float4*)(cls + ((size_t)b * K_ + (size_t)k0) * C_);

    float a0 = 0.0f, a1 = 0.0f, a2 = 0.0f, a3 = 0.0f;

    if (na == CHUNK) {
        const int NIT = CHUNK * (C_ / 4) / BLOCK;   // 20, compile-time
#pragma unroll 10
        for (int it = 0; it < NIT; ++it) {
            int idx = tid + it * BLOCK;
            int a_l = (idx * 3277) >> 16;           // idx/20, exact for idx<5120
            float mm = s_m[a_l];
            float4 x = cp[idx];
            a0 = fmaf(mm, fast_sqrt(x.x) * fast_log2(1.0f - x.x), a0);
            a1 = fmaf(mm, fast_sqrt(x.y) * fast_log2(1.0f - x.y), a1);
            a2 = fmaf(mm, fast_sqrt(x.z) * fast_log2(1.0f - x.z), a2);
            a3 = fmaf(mm, fast_sqrt(x.w) * fast_log2(1.0f - x.w), a3);
        }
    } else {
        for (int idx = tid; idx < nf4; idx += BLOCK) {
            int a_l = (idx * 3277) >> 16;
            float mm = s_m[a_l];
            float4 x = cp[idx];
            a0 = fmaf(mm, fast_sqrt(x.x) * fast_log2(1.0f - x.x), a0);
            a1 = fmaf(mm, fast_sqrt(x.y) * fast_log2(1.0f - x.y), a1);
            a2 = fmaf(mm, fast_sqrt(x.z) * fast_log2(1.0f - x.z), a2);
            a3 = fmaf(mm, fast_sqrt(x.w) * fast_log2(1.0f - x.w), a3);
        }
    }

    float cls_acc = ((a0 + a1) + (a2 + a3)) * (-0.75f * LN2) + cls_corr;

    // ---- block reduction of (cls_acc, reg_acc, np_acc) ----
    float v0 = cls_acc, v1 = reg_acc, v2 = np_acc;
    for (int off = 32; off > 0; off >>= 1) {
        v0 += __shfl_down(v0, off, 64);
        v1 += __shfl_down(v1, off, 64);
        v2 += __shfl_down(v2, off, 64);
    }
    int wave = tid >> 6, lane = tid & 63;
    if (lane == 0) {
        s_red[wave * 3 + 0] = v0;
        s_red[wave * 3 + 1] = v1;
        s_red[wave * 3 + 2] = v2;
    }
    BAR();
    if (tid == 0) {
        float c = 0.0f, rg = 0.0f, np = 0.0f;
        for (int w = 0; w < BLOCK / 64; ++w) {
            c  += s_red[w * 3 + 0];
            rg += s_red[w * 3 + 1];
            np += s_red[w * 3 + 2];
        }
        atomicAdd(&ws[b * 3 + 0], c);
        atomicAdd(&ws[b * 3 + 1], rg);
        atomicAdd(&ws[b * 3 + 2], np);

        // ---- last finishing block performs the finalize (saves a dispatch) ----
        __threadfence();                            // release: adds visible first
        unsigned prev = atomicAdd((unsigned int*)(ws + 3 * B_), 1u);
        if (prev == (unsigned)(TOTAL_BLOCKS - 1)) {
            __threadfence();                        // acquire
            float cs = 0.0f, rs = 0.0f;
            for (int bb = 0; bb < B_; ++bb) {
                // atomic RMW reads: coherent across XCDs (plain loads could hit stale L2)
                float cc  = atomicAdd(&ws[bb * 3 + 0], 0.0f);
                float rr  = atomicAdd(&ws[bb * 3 + 1], 0.0f);
                float nn  = atomicAdd(&ws[bb * 3 + 2], 0.0f);
                cs += cc / fmaxf(nn, 1.0f);
                rs += (nn > 0.0f) ? rr / fmaxf(nn * 4.0f, 1.0f) : 0.0f;
            }
            out[0] = cs / (float)B_;
            out[1] = rs / (float)B_;
        }
    }
}

extern "C" void kernel_launch(void* const* d_in, const int* in_sizes, int n_in,
                              void* d_out, int out_size, void* d_ws, size_t ws_size,
                              hipStream_t stream) {
    const float* cls = (const float*)d_in[0];   // [B,K,C]
    const float* reg = (const float*)d_in[1];   // [B,K,4]
    const float* anc = (const float*)d_in[2];   // [1,K,4]
    const float* ann = (const float*)d_in[3];   // [B,NANN,5]
    float* out = (float*)d_out;                  // [2]
    float* ws  = (float*)d_ws;                   // 25 floats: per-batch {cls,reg,npos} + counter

    zero_ws_kernel<<<1, 64, 0, stream>>>(ws);

    dim3 grid(NBLK_X, B_);
    focal_main<<<grid, BLOCK, 0, stream>>>(cls, reg, anc, ann, ws, out);
}

// Round 5
// 388.465 us; speedup vs baseline: 1.3342x; 1.3342x over previous
//
#include <hip/hip_runtime.h>
#include <math.h>

#define B_ 8
#define K_ 100000
#define NANN 32
#define C_ 80
#define BLOCK 256
#define CHUNK 256           // anchors per block
#define LN2 0.69314718056f
#define NBLK_X ((K_ + CHUNK - 1) / CHUNK)

__global__ void zero_ws_kernel(float* ws) {
    int i = threadIdx.x;
    if (i < 3 * B_) ws[i] = 0.0f;
}

__device__ __forceinline__ float fast_log2(float x) {
#if __has_builtin(__builtin_amdgcn_logf)
    return __builtin_amdgcn_logf(x);      // raw v_log_f32 (log2)
#else
    return __log2f(x);
#endif
}
__device__ __forceinline__ float fast_sqrt(float x) {
#if __has_builtin(__builtin_amdgcn_sqrtf)
    return __builtin_amdgcn_sqrtf(x);     // raw v_sqrt_f32
#else
    return sqrtf(x);
#endif
}

// LDS-only barrier: waits ds ops (lgkmcnt) but leaves global loads (vmcnt) in
// flight — unlike __syncthreads(), which drains vmcnt(0). Every barrier in this
// kernel only orders LDS (s_ann / s_m / s_red). All BAR() sites are in uniform
// control flow (no early return), so the raw s_barrier cannot deadlock.
// NOTE round-3/4 lesson: the regression there was the per-block __threadfence()
// (L2 wb/inv x3128) in the fused finalize — NOT this barrier. Fused finalize
// is removed; finalize is a separate dispatch again.
#define BAR() do { \
    asm volatile("s_waitcnt lgkmcnt(0)" ::: "memory"); \
    __builtin_amdgcn_s_barrier(); \
} while (0)

__launch_bounds__(BLOCK)
__global__ void focal_main(const float* __restrict__ cls,
                           const float* __restrict__ reg,
                           const float* __restrict__ anc,
                           const float* __restrict__ ann,
                           float* __restrict__ ws) {
    const int b     = blockIdx.y;
    const int chunk = blockIdx.x;
    const int tid   = threadIdx.x;

    __shared__ float s_ann[NANN * 5];
    __shared__ float s_m[CHUNK];               // 0 = ignore, 1 = count (neg or pos)
    __shared__ float s_red[(BLOCK / 64) * 3];

    const int k0 = chunk * CHUNK;
    const int k  = k0 + tid;
    const bool kval = (k < K_);

    // ---- early long-latency loads: anchor + annotation staging ----
    float4 a = make_float4(0.f, 0.f, 0.f, 0.f);
    if (kval) a = *(const float4*)(anc + (size_t)k * 4);

    // stage annotations as float4 (160 floats = 40 float4)
    if (tid < NANN * 5 / 4)
        ((float4*)s_ann)[tid] = ((const float4*)(ann + (size_t)b * NANN * 5))[tid];
    BAR();

    float reg_acc  = 0.0f;
    float np_acc   = 0.0f;
    float cls_corr = 0.0f;   // positive-anchor class-term swap (exact units)
    float m        = 0.0f;

    if (kval) {
        float aw = a.z - a.x, ah = a.w - a.y;
        float area_a = aw * ah;

        float best = -2.0f;
        int bestj = 0;
        for (int j = 0; j < NANN; ++j) {
            float bx1 = s_ann[j * 5 + 0], by1 = s_ann[j * 5 + 1];
            float bx2 = s_ann[j * 5 + 2], by2 = s_ann[j * 5 + 3];
            float lbl = s_ann[j * 5 + 4];
            float area_b = (bx2 - bx1) * (by2 - by1);
            float iw = fmaxf(fminf(a.z, bx2) - fmaxf(a.x, bx1), 0.0f);
            float ih = fmaxf(fminf(a.w, by2) - fmaxf(a.y, by1), 0.0f);
            float inter = iw * ih;
            float uni = fmaxf(area_a + area_b - inter, 1e-8f);
            float iou = inter / uni;
            if (lbl < 0.0f) iou = -1.0f;            // invalid annotation mask
            if (iou > best) { best = iou; bestj = j; }  // first-max = jnp.argmax
        }

        if (best >= 0.5f) {                         // positive anchor
            m = 1.0f;
            np_acc = 1.0f;
            int c = (int)s_ann[bestj * 5 + 4];
            // correction: sweep will apply the NEG formula at class c; swap it
            // for the POS formula. p in (0.01,0.99) -> clamp is a no-op.
            float p  = cls[((size_t)b * K_ + k) * C_ + c];
            float pm = 1.0f - p;
            float pos_term = -0.25f * fast_sqrt(pm) * (fast_log2(p)  * LN2);
            float neg_term = -0.75f * fast_sqrt(p)  * (fast_log2(pm) * LN2);
            cls_corr = pos_term - neg_term;

            // regression smooth-L1
            float gx1 = s_ann[bestj * 5 + 0], gy1 = s_ann[bestj * 5 + 1];
            float gx2 = s_ann[bestj * 5 + 2], gy2 = s_ann[bestj * 5 + 3];
            float gw = fmaxf(gx2 - gx1, 1.0f);
            float gh = fmaxf(gy2 - gy1, 1.0f);
            float gcx = gx1 + 0.5f * gw, gcy = gy1 + 0.5f * gh;
            float acx = a.x + 0.5f * aw, acy = a.y + 0.5f * ah;
            float4 r = *(const float4*)(reg + ((size_t)b * K_ + k) * 4);
            float t0 = ((gcx - acx) / aw) * 10.0f;
            float t1 = ((gcy - acy) / ah) * 10.0f;
            float t2 = (fast_log2(gw / aw) * LN2) * 5.0f;
            float t3 = (fast_log2(gh / ah) * LN2) * 5.0f;
            float d, s;
            d = fabsf(t0 - r.x); s = (d <= 1.0f/9.0f) ? 4.5f*d*d : d - 0.5f/9.0f; reg_acc += s;
            d = fabsf(t1 - r.y); s = (d <= 1.0f/9.0f) ? 4.5f*d*d : d - 0.5f/9.0f; reg_acc += s;
            d = fabsf(t2 - r.z); s = (d <= 1.0f/9.0f) ? 4.5f*d*d : d - 0.5f/9.0f; reg_acc += s;
            d = fabsf(t3 - r.w); s = (d <= 1.0f/9.0f) ? 4.5f*d*d : d - 0.5f/9.0f; reg_acc += s;
        } else if (best < 0.4f) {
            m = 1.0f;                               // negative anchor
        } // else ignore: m = 0
    }
    s_m[tid] = m;
    BAR();

    // ---- classification sweep: acc = sum m * sqrt(p) * log2(1-p) ----
    // Round-0-proven form: plain cached loads, #pragma unroll 5, compiler-
    // scheduled. (Round-3/4 lesson: nt loads / manual prefetch / unroll 10
    // were all neutral-to-negative; the big regression was the fused-finalize
    // threadfence, now removed.)
    const int na  = min(CHUNK, K_ - k0);
    const int nf4 = na * (C_ / 4);
    const float4* __restrict__ cp =
        (const float4*)(cls + ((size_t)b * K_ + (size_t)k0) * C_);

    float a0 = 0.0f, a1 = 0.0f, a2 = 0.0f, a3 = 0.0f;

    if (na == CHUNK) {
        const int NIT = CHUNK * (C_ / 4) / BLOCK;   // 20, compile-time
#pragma unroll 5
        for (int it = 0; it < NIT; ++it) {
            int idx = tid + it * BLOCK;
            int a_l = (idx * 3277) >> 16;           // idx/20, exact for idx<5120
            float mm = s_m[a_l];
            float4 x = cp[idx];
            a0 = fmaf(mm, fast_sqrt(x.x) * fast_log2(1.0f - x.x), a0);
            a1 = fmaf(mm, fast_sqrt(x.y) * fast_log2(1.0f - x.y), a1);
            a2 = fmaf(mm, fast_sqrt(x.z) * fast_log2(1.0f - x.z), a2);
            a3 = fmaf(mm, fast_sqrt(x.w) * fast_log2(1.0f - x.w), a3);
        }
    } else {
        for (int idx = tid; idx < nf4; idx += BLOCK) {
            int a_l = (idx * 3277) >> 16;
            float mm = s_m[a_l];
            float4 x = cp[idx];
            a0 = fmaf(mm, fast_sqrt(x.x) * fast_log2(1.0f - x.x), a0);
            a1 = fmaf(mm, fast_sqrt(x.y) * fast_log2(1.0f - x.y), a1);
            a2 = fmaf(mm, fast_sqrt(x.z) * fast_log2(1.0f - x.z), a2);
            a3 = fmaf(mm, fast_sqrt(x.w) * fast_log2(1.0f - x.w), a3);
        }
    }

    float cls_acc = ((a0 + a1) + (a2 + a3)) * (-0.75f * LN2) + cls_corr;

    // ---- block reduction of (cls_acc, reg_acc, np_acc) ----
    float v0 = cls_acc, v1 = reg_acc, v2 = np_acc;
    for (int off = 32; off > 0; off >>= 1) {
        v0 += __shfl_down(v0, off, 64);
        v1 += __shfl_down(v1, off, 64);
        v2 += __shfl_down(v2, off, 64);
    }
    int wave = tid >> 6, lane = tid & 63;
    if (lane == 0) {
        s_red[wave * 3 + 0] = v0;
        s_red[wave * 3 + 1] = v1;
        s_red[wave * 3 + 2] = v2;
    }
    BAR();
    if (tid == 0) {
        float c = 0.0f, rg = 0.0f, np = 0.0f;
        for (int w = 0; w < BLOCK / 64; ++w) {
            c  += s_red[w * 3 + 0];
            rg += s_red[w * 3 + 1];
            np += s_red[w * 3 + 2];
        }
        atomicAdd(&ws[b * 3 + 0], c);
        atomicAdd(&ws[b * 3 + 1], rg);
        atomicAdd(&ws[b * 3 + 2], np);
    }
}

__global__ void finalize_kernel(const float* __restrict__ ws, float* __restrict__ out) {
    if (threadIdx.x == 0) {
        float cs = 0.0f, rs = 0.0f;
        for (int b = 0; b < B_; ++b) {
            float c  = ws[b * 3 + 0];
            float r  = ws[b * 3 + 1];
            float np = ws[b * 3 + 2];
            cs += c / fmaxf(np, 1.0f);
            rs += (np > 0.0f) ? r / fmaxf(np * 4.0f, 1.0f) : 0.0f;
        }
        out[0] = cs / (float)B_;
        out[1] = rs / (float)B_;
    }
}

extern "C" void kernel_launch(void* const* d_in, const int* in_sizes, int n_in,
                              void* d_out, int out_size, void* d_ws, size_t ws_size,
                              hipStream_t stream) {
    const float* cls = (const float*)d_in[0];   // [B,K,C]
    const float* reg = (const float*)d_in[1];   // [B,K,4]
    const float* anc = (const float*)d_in[2];   // [1,K,4]
    const float* ann = (const float*)d_in[3];   // [B,NANN,5]
    float* out = (float*)d_out;                  // [2]
    float* ws  = (float*)d_ws;                   // 24 floats: per-batch {cls,reg,npos}

    zero_ws_kernel<<<1, 64, 0, stream>>>(ws);

    dim3 grid(NBLK_X, B_);
    focal_main<<<grid, BLOCK, 0, stream>>>(cls, reg, anc, ann, ws);

    finalize_kernel<<<1, 64, 0, stream>>>(ws, out);
}

// Round 6
// 378.382 us; speedup vs baseline: 1.3698x; 1.0266x over previous
//
#include <hip/hip_runtime.h>
#include <math.h>

#define B_ 8
#define K_ 100000
#define NANN 32
#define C_ 80
#define BLOCK 256
#define CHUNK 256           // anchors per block
#define LN2 0.69314718056f
#define NBLK_X ((K_ + CHUNK - 1) / CHUNK)

__global__ void zero_ws_kernel(float* ws) {
    int i = threadIdx.x;
    if (i < 3 * B_) ws[i] = 0.0f;
}

__device__ __forceinline__ float fast_log2(float x) {
#if __has_builtin(__builtin_amdgcn_logf)
    return __builtin_amdgcn_logf(x);      // raw v_log_f32 (log2)
#else
    return __log2f(x);
#endif
}
__device__ __forceinline__ float fast_sqrt(float x) {
#if __has_builtin(__builtin_amdgcn_sqrtf)
    return __builtin_amdgcn_sqrtf(x);     // raw v_sqrt_f32
#else
    return sqrtf(x);
#endif
}

// Session lessons (rounds 3-5):
//  - __threadfence() per block (fused finalize) = L2 wb/inv x3128 -> +130 us. NEVER.
//  - nontemporal cls loads lose L3 residency (FETCH shows ~half of cls is
//    L3-served across iterations) -> 634 GB/s floor. Keep cached loads.
//  - manual rolling vmcnt-deep prefetch in the sweep serializes on latency. Keep
//    the compiler-scheduled unroll-5 loop.
//  - plain __syncthreads() everywhere; the only prefetch that survives it is one
//    issued a full compute-phase before the barrier (drain is then free).

__launch_bounds__(BLOCK)
__global__ void focal_main(const float* __restrict__ cls,
                           const float* __restrict__ reg,
                           const float* __restrict__ anc,
                           const float* __restrict__ ann,
                           float* __restrict__ ws) {
    const int b     = blockIdx.y;
    const int chunk = blockIdx.x;
    const int tid   = threadIdx.x;

    __shared__ float s_ann[NANN * 5];
    __shared__ float s_m[CHUNK];               // 0 = ignore, 1 = count (neg or pos)
    __shared__ float s_red[(BLOCK / 64) * 3];

    const int k0 = chunk * CHUNK;
    const int k  = k0 + tid;
    const bool kval = (k < K_);
    const bool full = (k0 + CHUNK <= K_);      // block-uniform

    const float4* __restrict__ cp =
        (const float4*)(cls + ((size_t)b * K_ + (size_t)k0) * C_);

    // ---- early anchor load: overlaps the annotation staging latency ----
    float4 a = make_float4(0.f, 0.f, 0.f, 0.f);
    if (kval) a = *(const float4*)(anc + (size_t)k * 4);

    // stage annotations as float4 (160 floats = 40 float4)
    if (tid < NANN * 5 / 4)
        ((float4*)s_ann)[tid] = ((const float4*)(ann + (size_t)b * NANN * 5))[tid];
    __syncthreads();

    // ---- issue the first 2 sweep loads NOW: they land during the IoU phase,
    //      so the vmcnt drain at the next __syncthreads() is nearly free and the
    //      sweep starts with warm data instead of a ~900-cy HBM stall.
    float4 pf0 = make_float4(0.f, 0.f, 0.f, 0.f);
    float4 pf1 = make_float4(0.f, 0.f, 0.f, 0.f);
    if (full) {
        pf0 = cp[tid];
        pf1 = cp[tid + BLOCK];
    }

    float reg_acc  = 0.0f;
    float np_acc   = 0.0f;
    float cls_corr = 0.0f;   // positive-anchor class-term swap (exact units)
    float m        = 0.0f;

    if (kval) {
        float aw = a.z - a.x, ah = a.w - a.y;
        float area_a = aw * ah;

        float best = -2.0f;
        int bestj = 0;
        for (int j = 0; j < NANN; ++j) {
            float bx1 = s_ann[j * 5 + 0], by1 = s_ann[j * 5 + 1];
            float bx2 = s_ann[j * 5 + 2], by2 = s_ann[j * 5 + 3];
            float lbl = s_ann[j * 5 + 4];
            float area_b = (bx2 - bx1) * (by2 - by1);
            float iw = fmaxf(fminf(a.z, bx2) - fmaxf(a.x, bx1), 0.0f);
            float ih = fmaxf(fminf(a.w, by2) - fmaxf(a.y, by1), 0.0f);
            float inter = iw * ih;
            float uni = fmaxf(area_a + area_b - inter, 1e-8f);
            float iou = inter / uni;
            if (lbl < 0.0f) iou = -1.0f;            // invalid annotation mask
            if (iou > best) { best = iou; bestj = j; }  // first-max = jnp.argmax
        }

        if (best >= 0.5f) {                         // positive anchor
            m = 1.0f;
            np_acc = 1.0f;
            int c = (int)s_ann[bestj * 5 + 4];
            // correction: sweep will apply the NEG formula at class c; swap it
            // for the POS formula. p in (0.01,0.99) -> clamp is a no-op.
            float p  = cls[((size_t)b * K_ + k) * C_ + c];
            float pm = 1.0f - p;
            float pos_term = -0.25f * fast_sqrt(pm) * (fast_log2(p)  * LN2);
            float neg_term = -0.75f * fast_sqrt(p)  * (fast_log2(pm) * LN2);
            cls_corr = pos_term - neg_term;

            // regression smooth-L1
            float gx1 = s_ann[bestj * 5 + 0], gy1 = s_ann[bestj * 5 + 1];
            float gx2 = s_ann[bestj * 5 + 2], gy2 = s_ann[bestj * 5 + 3];
            float gw = fmaxf(gx2 - gx1, 1.0f);
            float gh = fmaxf(gy2 - gy1, 1.0f);
            float gcx = gx1 + 0.5f * gw, gcy = gy1 + 0.5f * gh;
            float acx = a.x + 0.5f * aw, acy = a.y + 0.5f * ah;
            float4 r = *(const float4*)(reg + ((size_t)b * K_ + k) * 4);
            float t0 = ((gcx - acx) / aw) * 10.0f;
            float t1 = ((gcy - acy) / ah) * 10.0f;
            float t2 = (fast_log2(gw / aw) * LN2) * 5.0f;
            float t3 = (fast_log2(gh / ah) * LN2) * 5.0f;
            float d, s;
            d = fabsf(t0 - r.x); s = (d <= 1.0f/9.0f) ? 4.5f*d*d : d - 0.5f/9.0f; reg_acc += s;
            d = fabsf(t1 - r.y); s = (d <= 1.0f/9.0f) ? 4.5f*d*d : d - 0.5f/9.0f; reg_acc += s;
            d = fabsf(t2 - r.z); s = (d <= 1.0f/9.0f) ? 4.5f*d*d : d - 0.5f/9.0f; reg_acc += s;
            d = fabsf(t3 - r.w); s = (d <= 1.0f/9.0f) ? 4.5f*d*d : d - 0.5f/9.0f; reg_acc += s;
        } else if (best < 0.4f) {
            m = 1.0f;                               // negative anchor
        } // else ignore: m = 0
    }
    s_m[tid] = m;
    __syncthreads();

    // ---- classification sweep: acc = sum m * sqrt(p) * log2(1-p) ----
    const int na  = min(CHUNK, K_ - k0);
    const int nf4 = na * (C_ / 4);

    float a0 = 0.0f, a1 = 0.0f, a2 = 0.0f, a3 = 0.0f;

    if (na == CHUNK) {
        // iterations 0-1 consume the prefetched registers (named, static -
        // rule #20: no runtime-indexed register arrays)
        {
            int a_l = (tid * 3277) >> 16;           // idx/20, exact for idx<5120
            float mm = s_m[a_l];
            a0 = fmaf(mm, fast_sqrt(pf0.x) * fast_log2(1.0f - pf0.x), a0);
            a1 = fmaf(mm, fast_sqrt(pf0.y) * fast_log2(1.0f - pf0.y), a1);
            a2 = fmaf(mm, fast_sqrt(pf0.z) * fast_log2(1.0f - pf0.z), a2);
            a3 = fmaf(mm, fast_sqrt(pf0.w) * fast_log2(1.0f - pf0.w), a3);
        }
        {
            int idx = tid + BLOCK;
            int a_l = (idx * 3277) >> 16;
            float mm = s_m[a_l];
            a0 = fmaf(mm, fast_sqrt(pf1.x) * fast_log2(1.0f - pf1.x), a0);
            a1 = fmaf(mm, fast_sqrt(pf1.y) * fast_log2(1.0f - pf1.y), a1);
            a2 = fmaf(mm, fast_sqrt(pf1.z) * fast_log2(1.0f - pf1.z), a2);
            a3 = fmaf(mm, fast_sqrt(pf1.w) * fast_log2(1.0f - pf1.w), a3);
        }
        const int NIT = CHUNK * (C_ / 4) / BLOCK;   // 20, compile-time
#pragma unroll 6
        for (int it = 2; it < NIT; ++it) {          // 18 iters, unroll 6
            int idx = tid + it * BLOCK;
            int a_l = (idx * 3277) >> 16;
            float mm = s_m[a_l];
            float4 x = cp[idx];
            a0 = fmaf(mm, fast_sqrt(x.x) * fast_log2(1.0f - x.x), a0);
            a1 = fmaf(mm, fast_sqrt(x.y) * fast_log2(1.0f - x.y), a1);
            a2 = fmaf(mm, fast_sqrt(x.z) * fast_log2(1.0f - x.z), a2);
            a3 = fmaf(mm, fast_sqrt(x.w) * fast_log2(1.0f - x.w), a3);
        }
    } else {
        for (int idx = tid; idx < nf4; idx += BLOCK) {
            int a_l = (idx * 3277) >> 16;
            float mm = s_m[a_l];
            float4 x = cp[idx];
            a0 = fmaf(mm, fast_sqrt(x.x) * fast_log2(1.0f - x.x), a0);
            a1 = fmaf(mm, fast_sqrt(x.y) * fast_log2(1.0f - x.y), a1);
            a2 = fmaf(mm, fast_sqrt(x.z) * fast_log2(1.0f - x.z), a2);
            a3 = fmaf(mm, fast_sqrt(x.w) * fast_log2(1.0f - x.w), a3);
        }
    }

    float cls_acc = ((a0 + a1) + (a2 + a3)) * (-0.75f * LN2) + cls_corr;

    // ---- block reduction of (cls_acc, reg_acc, np_acc) ----
    float v0 = cls_acc, v1 = reg_acc, v2 = np_acc;
    for (int off = 32; off > 0; off >>= 1) {
        v0 += __shfl_down(v0, off, 64);
        v1 += __shfl_down(v1, off, 64);
        v2 += __shfl_down(v2, off, 64);
    }
    int wave = tid >> 6, lane = tid & 63;
    if (lane == 0) {
        s_red[wave * 3 + 0] = v0;
        s_red[wave * 3 + 1] = v1;
        s_red[wave * 3 + 2] = v2;
    }
    __syncthreads();
    if (tid == 0) {
        float c = 0.0f, rg = 0.0f, np = 0.0f;
        for (int w = 0; w < BLOCK / 64; ++w) {
            c  += s_red[w * 3 + 0];
            rg += s_red[w * 3 + 1];
            np += s_red[w * 3 + 2];
        }
        atomicAdd(&ws[b * 3 + 0], c);
        atomicAdd(&ws[b * 3 + 1], rg);
        atomicAdd(&ws[b * 3 + 2], np);
    }
}

__global__ void finalize_kernel(const float* __restrict__ ws, float* __restrict__ out) {
    if (threadIdx.x == 0) {
        float cs = 0.0f, rs = 0.0f;
        for (int b = 0; b < B_; ++b) {
            float c  = ws[b * 3 + 0];
            float r  = ws[b * 3 + 1];
            float np = ws[b * 3 + 2];
            cs += c / fmaxf(np, 1.0f);
            rs += (np > 0.0f) ? r / fmaxf(np * 4.0f, 1.0f) : 0.0f;
        }
        out[0] = cs / (float)B_;
        out[1] = rs / (float)B_;
    }
}

extern "C" void kernel_launch(void* const* d_in, const int* in_sizes, int n_in,
                              void* d_out, int out_size, void* d_ws, size_t ws_size,
                              hipStream_t stream) {
    const float* cls = (const float*)d_in[0];   // [B,K,C]
    const float* reg = (const float*)d_in[1];   // [B,K,4]
    const float* anc = (const float*)d_in[2];   // [1,K,4]
    const float* ann = (const float*)d_in[3];   // [B,NANN,5]
    float* out = (float*)d_out;                  // [2]
    float* ws  = (float*)d_ws;                   // 24 floats: per-batch {cls,reg,npos}

    zero_ws_kernel<<<1, 64, 0, stream>>>(ws);

    dim3 grid(NBLK_X, B_);
    focal_main<<<grid, BLOCK, 0, stream>>>(cls, reg, anc, ann, ws);

    finalize_kernel<<<1, 64, 0, stream>>>(ws, out);
}